// Round 8
// baseline (60.293 us; speedup 1.0000x reference)
//
#include <hip/hip_runtime.h>

// Problem constants (fixed by reference setup_inputs)
#define BN 512
#define CCH 32
#define TT 4096
#define RPB 8   // rows per block; grid = BN*CCH/RPB = 2048 (8 blocks/CU queued)

// Pad LDS by +4 floats per 32: float4 (16B) staging writes stay 16B-aligned
// (4-aligned idx -> 4-aligned padded idx); per-lane b128 bin reads get their
// start banks spread across lanes -> ~conflict-free.
// Writes and reads BOTH use ABSOLUTE element indices.
__device__ __forceinline__ int padidx(int i) { return i + ((i >> 5) << 2); }
// padidx of the first element of float4-block b: padidx(4b) = 4b + ((b>>3)<<2)
__device__ __forceinline__ int padblk(int b) { return (b << 2) + ((b >> 3) << 2); }

__global__ __launch_bounds__(256) void pool_pipe3(
    const float* __restrict__ f, const float* __restrict__ m,
    const int* __restrict__ vlen,
    float* __restrict__ out_f, float* __restrict__ out_m, int K)
{
    __shared__ float sf[4608];   // padidx(4095) = 4603 < 4608
    __shared__ float sm[4608];

    const int tid = threadIdx.x;
    const int nb_grid = gridDim.x;

    // valid_lengths may be int64 (JAX x64 on) or int32 (x64 off).
    // int64 LE: all high words are 0 since values < 4096.
    bool is64 = ((vlen[1] | vlen[3] | vlen[5] | vlen[7] |
                  vlen[9] | vlen[11] | vlen[13] | vlen[15]) == 0);

    // Named float4 prefetch registers (static indices -> stay in VGPRs).
    float4 rf0, rf1, rf2, rf3, rm0, rm1, rm2, rm3;
    int bc, L, off, a0, nv;

    #define ROW_PARAMS(j)                                              \
        do {                                                           \
            bc = blockIdx.x + (j) * nb_grid;                           \
            int b_ = bc / CCH;                                         \
            int len_ = is64 ? vlen[2 * b_] : vlen[b_];                 \
            L = len_ < 1 ? 1 : (len_ > TT ? TT : len_);                \
            off = TT - L;                                              \
            a0 = off & ~3;                                             \
            nv = (TT - a0) >> 2;                                       \
        } while (0)

    #define ISSUE_LOADS()                                              \
        do {                                                           \
            const float* fr_ = f + (size_t)bc * TT + a0;               \
            const float* mr_ = m + (size_t)bc * TT + a0;               \
            int i0_ = tid, i1_ = tid + 256, i2_ = tid + 512, i3_ = tid + 768; \
            if (i0_ < nv) { rf0 = *(const float4*)(fr_ + 4 * i0_);     \
                            rm0 = *(const float4*)(mr_ + 4 * i0_); }   \
            if (i1_ < nv) { rf1 = *(const float4*)(fr_ + 4 * i1_);     \
                            rm1 = *(const float4*)(mr_ + 4 * i1_); }   \
            if (i2_ < nv) { rf2 = *(const float4*)(fr_ + 4 * i2_);     \
                            rm2 = *(const float4*)(mr_ + 4 * i2_); }   \
            if (i3_ < nv) { rf3 = *(const float4*)(fr_ + 4 * i3_);     \
                            rm3 = *(const float4*)(mr_ + 4 * i3_); }   \
        } while (0)

    // Prologue: prefetch row 0.
    ROW_PARAMS(0);
    ISSUE_LOADS();

    for (int j = 0; j < RPB; ++j) {
        // Write the prefetched row into LDS (absolute padded indices).
        {
            int i0_ = tid, i1_ = tid + 256, i2_ = tid + 512, i3_ = tid + 768;
            if (i0_ < nv) { int p = padidx(a0 + 4 * i0_);
                            *(float4*)&sf[p] = rf0; *(float4*)&sm[p] = rm0; }
            if (i1_ < nv) { int p = padidx(a0 + 4 * i1_);
                            *(float4*)&sf[p] = rf1; *(float4*)&sm[p] = rm1; }
            if (i2_ < nv) { int p = padidx(a0 + 4 * i2_);
                            *(float4*)&sf[p] = rf2; *(float4*)&sm[p] = rm2; }
            if (i3_ < nv) { int p = padidx(a0 + 4 * i3_);
                            *(float4*)&sf[p] = rf3; *(float4*)&sm[p] = rm3; }
        }
        __syncthreads();

        int cbc = bc, cL = L, coff = off;

        // Issue next row's global loads NOW — they fly during bin-compute.
        if (j + 1 < RPB) {
            ROW_PARAMS(j + 1);
            ISSUE_LOADS();
        }

        // Bin-compute: one bin per thread, 5 clamped b128 reads per array,
        // ABSOLUTE indices throughout.
        for (int k = tid; k < K; k += 256) {
            unsigned uL = (unsigned)cL, uK = (unsigned)K, uk = (unsigned)k;
            int si = coff + (int)((uL * uk) / uK);
            int ei = coff + (int)((uL * (uk + 1u) + uK - 1u) / uK);
            if (ei > TT) ei = TT;
            int count = ei - si;
            if (count < 1) count = 1;

            int re = ei - 1;             // absolute last element
            int b0 = si >> 2;            // absolute first block
            int nbw = (re >> 2) - b0;    // 0..4 extra blocks

            float af = 0.0f, am = 0.0f;
#define ACCB(J)                                                            \
    do {                                                                   \
        int bj = b0 + ((nbw < (J)) ? nbw : (J));                           \
        int p  = padblk(bj);                                               \
        float4 F = *(const float4*)&sf[p];                                 \
        float4 M = *(const float4*)&sm[p];                                 \
        bool oki = ((J) <= nbw);                                           \
        int u = bj << 2;                                                   \
        { float w = (oki && u     >= si && u     <= re) ? 1.f : 0.f;       \
          af = fmaf(w, F.x, af); am = fmaf(w, M.x, am); }                  \
        { float w = (oki && u + 1 >= si && u + 1 <= re) ? 1.f : 0.f;       \
          af = fmaf(w, F.y, af); am = fmaf(w, M.y, am); }                  \
        { float w = (oki && u + 2 >= si && u + 2 <= re) ? 1.f : 0.f;       \
          af = fmaf(w, F.z, af); am = fmaf(w, M.z, am); }                  \
        { float w = (oki && u + 3 >= si && u + 3 <= re) ? 1.f : 0.f;       \
          af = fmaf(w, F.w, af); am = fmaf(w, M.w, am); }                  \
    } while (0)
            ACCB(0); ACCB(1); ACCB(2); ACCB(3); ACCB(4);
#undef ACCB

            float inv = 1.0f / (float)count;
            size_t o = (size_t)cbc * K + k;
            out_f[o] = af * inv;
            out_m[o] = am * inv;
        }
        __syncthreads();
    }
    #undef ROW_PARAMS
    #undef ISSUE_LOADS
}

extern "C" void kernel_launch(void* const* d_in, const int* in_sizes, int n_in,
                              void* d_out, int out_size, void* d_ws, size_t ws_size,
                              hipStream_t stream) {
    const float* f    = (const float*)d_in[0];
    const float* m    = (const float*)d_in[1];
    const int*   vlen = (const int*)d_in[2];

    // K derived from output size: out = 2 * BN * C * K floats
    int K = out_size / (2 * BN * CCH);
    if (K < 1) K = 1;

    float* out_f = (float*)d_out;
    float* out_m = out_f + (size_t)BN * CCH * K;

    int grid = (BN * CCH) / RPB;   // 2048
    pool_pipe3<<<grid, 256, 0, stream>>>(f, m, vlen, out_f, out_m, K);
}

// Round 9
// 56.699 us; speedup vs baseline: 1.0634x; 1.0634x over previous
//
#include <hip/hip_runtime.h>

// Problem constants (fixed by reference setup_inputs)
#define BN 512
#define CCH 32
#define TT 4096
#define RPB 4   // rows per block; grid = BN*CCH/RPB = 4096

// Pad LDS by +4 floats per 32: float4 staging writes keep 16B alignment,
// scalar bin reads get spread across banks. Absolute element indices.
__device__ __forceinline__ int padidx(int i) { return i + ((i >> 5) << 2); }

__global__ __launch_bounds__(256) void pool_phased(
    const float* __restrict__ f, const float* __restrict__ m,
    const int* __restrict__ vlen,
    float* __restrict__ out_f, float* __restrict__ out_m,
    int K, int kshift)
{
    __shared__ float sb[4608];   // ONE array at a time: 18.4 KB -> 8 blocks/CU

    const int tid = threadIdx.x;
    const int nb  = gridDim.x;

    // valid_lengths may be int64 (JAX x64 on) or int32 (x64 off).
    // int64 LE: all high words are 0 since values < 4096.
    bool is64 = ((vlen[1] | vlen[3] | vlen[5] | vlen[7] |
                  vlen[9] | vlen[11] | vlen[13] | vlen[15]) == 0);

    // Prefetch registers (one array slice of one row).
    float4 r0, r1, r2, r3;
    // Current-row params.
    int cbc, cL, coff, ca0, cnv;
    // Params describing R's contents (LDS placement of pending write).
    int wa0, wnv;

    #define ROWP(J, BC, L_, OFF, A0, NV)                               \
        do {                                                           \
            BC = blockIdx.x + (J) * nb;                                \
            int b_ = (BC) >> 5;            /* /CCH, CCH=32 */          \
            int len_ = is64 ? vlen[2 * b_] : vlen[b_];                 \
            L_ = len_ < 1 ? 1 : (len_ > TT ? TT : len_);               \
            OFF = TT - L_;                                             \
            A0 = OFF & ~3;                                             \
            NV = (TT - A0) >> 2;                                       \
        } while (0)

    #define LOADR(SRC, NV)                                             \
        do {                                                           \
            int i0_ = tid, i1_ = tid + 256, i2_ = tid + 512, i3_ = tid + 768; \
            if (i0_ < (NV)) r0 = *(const float4*)((SRC) + 4 * i0_);    \
            if (i1_ < (NV)) r1 = *(const float4*)((SRC) + 4 * i1_);    \
            if (i2_ < (NV)) r2 = *(const float4*)((SRC) + 4 * i2_);    \
            if (i3_ < (NV)) r3 = *(const float4*)((SRC) + 4 * i3_);    \
        } while (0)

    #define WRITE_LDS()                                                \
        do {                                                           \
            int i0_ = tid, i1_ = tid + 256, i2_ = tid + 512, i3_ = tid + 768; \
            if (i0_ < wnv) { int p = padidx(wa0 + 4 * i0_); *(float4*)&sb[p] = r0; } \
            if (i1_ < wnv) { int p = padidx(wa0 + 4 * i1_); *(float4*)&sb[p] = r1; } \
            if (i2_ < wnv) { int p = padidx(wa0 + 4 * i2_); *(float4*)&sb[p] = r2; } \
            if (i3_ < wnv) { int p = padidx(wa0 + 4 * i3_); *(float4*)&sb[p] = r3; } \
        } while (0)

    #define COMPUTE(OUTP)                                              \
        for (int k = tid; k < K; k += 256) {                           \
            unsigned uL = (unsigned)cL, uK = (unsigned)K, uk = (unsigned)k; \
            unsigned q0 = uL * uk, q1 = uL * (uk + 1u) + uK - 1u;      \
            int si, ei;                                                \
            if (kshift >= 0) { si = coff + (int)(q0 >> kshift);        \
                               ei = coff + (int)(q1 >> kshift); }      \
            else             { si = coff + (int)(q0 / uK);             \
                               ei = coff + (int)(q1 / uK); }           \
            if (ei > TT) ei = TT;                                      \
            int count = ei - si; if (count < 1) count = 1;             \
            float acc = 0.0f;                                          \
            for (int t = si; t < ei; ++t) acc += sb[padidx(t)];        \
            (OUTP)[(size_t)cbc * K + k] = acc / (float)count;          \
        }

    // Prologue: params of row 0, issue f(row 0).
    ROWP(0, cbc, cL, coff, ca0, cnv);
    LOADR(f + (size_t)cbc * TT + ca0, cnv);
    wa0 = ca0; wnv = cnv;

    for (int j = 0; j < RPB; ++j) {
        // ---- phase f ----
        WRITE_LDS();                 // f(row j) -> LDS
        __syncthreads();
        LOADR(m + (size_t)cbc * TT + ca0, cnv);   // m(row j) in flight
        wa0 = ca0; wnv = cnv;
        COMPUTE(out_f);
        __syncthreads();

        // ---- phase m ----
        WRITE_LDS();                 // m(row j) -> LDS
        __syncthreads();
        if (j + 1 < RPB) {
            int nbc, nL, noff, na0, nnv;
            ROWP(j + 1, nbc, nL, noff, na0, nnv);
            LOADR(f + (size_t)nbc * TT + na0, nnv);   // f(row j+1) in flight
            wa0 = na0; wnv = nnv;
            COMPUTE(out_m);
            __syncthreads();
            cbc = nbc; cL = nL; coff = noff; ca0 = na0; cnv = nnv;
        } else {
            COMPUTE(out_m);
            __syncthreads();
        }
    }
    #undef ROWP
    #undef LOADR
    #undef WRITE_LDS
    #undef COMPUTE
}

extern "C" void kernel_launch(void* const* d_in, const int* in_sizes, int n_in,
                              void* d_out, int out_size, void* d_ws, size_t ws_size,
                              hipStream_t stream) {
    const float* f    = (const float*)d_in[0];
    const float* m    = (const float*)d_in[1];
    const int*   vlen = (const int*)d_in[2];

    // K derived from output size: out = 2 * BN * C * K floats
    int K = out_size / (2 * BN * CCH);
    if (K < 1) K = 1;
    int kshift = ((K & (K - 1)) == 0) ? __builtin_ctz(K) : -1;

    float* out_f = (float*)d_out;
    float* out_m = out_f + (size_t)BN * CCH * K;

    int grid = (BN * CCH) / RPB;   // 4096
    pool_phased<<<grid, 256, 0, stream>>>(f, m, vlen, out_f, out_m, K, kshift);
}